// Round 8
// baseline (203.894 us; speedup 1.0000x reference)
//
#include <hip/hip_runtime.h>
#include <hip/hip_bf16.h>

#define S_LEN 2048
#define DMODEL 1024
#define NHEAD 16
#define HD 64

typedef short short8 __attribute__((ext_vector_type(8)));
typedef short short4_t __attribute__((ext_vector_type(4)));
typedef float f32x4 __attribute__((ext_vector_type(4)));

// async global->LDS, 16B per lane; dest = wave-uniform base + lane*16
#define GLOAD_LDS16(gp, lp)                                        \
    __builtin_amdgcn_global_load_lds(                              \
        (__attribute__((address_space(1))) void*)(gp),             \
        (__attribute__((address_space(3))) void*)(lp), 16, 0, 0)

// fp32 -> bf16 (RNE) bit-level
__device__ inline unsigned short f2bf(float f) {
    union { float f; unsigned int u; } c;
    c.f = f;
    unsigned int r = c.u + 0x7fffu + ((c.u >> 16) & 1u);
    return (unsigned short)(r >> 16);
}

// ---------------------------------------------------------------------------
// Bulk cast fp32 -> bf16
// ---------------------------------------------------------------------------
__global__ __launch_bounds__(256) void cast_f32_bf16(
    const float* __restrict__ in, short* __restrict__ out, int n8)
{
    int i = blockIdx.x * 256 + threadIdx.x;
    if (i < n8) {
        float4 a = ((const float4*)in)[2 * i];
        float4 b = ((const float4*)in)[2 * i + 1];
        short8 o;
        o[0] = (short)f2bf(a.x); o[1] = (short)f2bf(a.y);
        o[2] = (short)f2bf(a.z); o[3] = (short)f2bf(a.w);
        o[4] = (short)f2bf(b.x); o[5] = (short)f2bf(b.y);
        o[6] = (short)f2bf(b.z); o[7] = (short)f2bf(b.w);
        ((short8*)out)[i] = o;
    }
}

// ---------------------------------------------------------------------------
// bf16 MFMA GEMM: C = A @ W^T + bias.  BM=BN=128, BK=64, 4 waves 2x2.
// NEW (r8): global_load_lds staging (linear LDS dest) with PRE-SWIZZLED
// global source; reads XOR the same involution (slot ^= row&7 on 16B slots),
// so each 16-lane fragment read spans 8 slot-banks (2-way, free) instead of
// the old unswizzled same-bank 8-way conflict.
// A/B k-slots keep the identical bijection (permutation-invariant MFMA).
// C/D mapping (HW-verified): col=lane&15, row=(lane>>4)*4+reg.
// ---------------------------------------------------------------------------
template<bool QKV>
__global__ __launch_bounds__(256) void gemm_mfma(
    const short* __restrict__ A, const short* __restrict__ W,
    const float* __restrict__ bias, float* __restrict__ C,
    int N, int K,
    short* __restrict__ qo, short* __restrict__ ko, short* __restrict__ vo)
{
    __shared__ __align__(16) short Ash[128 * 64];
    __shared__ __align__(16) short Bsh[128 * 64];

    const int tid = threadIdx.x;
    const int l = tid & 63;
    const int wid = tid >> 6;
    const int wr = wid >> 1, wc = wid & 1;
    const int n0 = blockIdx.x << 7, m0 = blockIdx.y << 7;

    const short* Abase = A + (size_t)m0 * K;
    const short* Wbase = W + (size_t)n0 * K;

    f32x4 acc[4][4];
    #pragma unroll
    for (int i = 0; i < 4; ++i)
        #pragma unroll
        for (int j = 0; j < 4; ++j)
            acc[i][j] = (f32x4)0.0f;

    // staging: chunk = i*256+tid -> dest row=chunk>>3, slot=chunk&7 (linear);
    // source slot pre-swizzled: (chunk&7) ^ (row&7)
    int rrow[4], scol[4];
    #pragma unroll
    for (int i = 0; i < 4; ++i) {
        int chunk = i * 256 + tid;
        rrow[i] = chunk >> 3;
        scol[i] = ((chunk & 7) ^ (rrow[i] & 7)) << 3;
    }

    const int NT = K >> 6;
    for (int kt = 0; kt < NT; ++kt) {
        const int k0 = kt << 6;
        __syncthreads();                 // previous compute done reading LDS
        #pragma unroll
        for (int i = 0; i < 4; ++i) {
            GLOAD_LDS16(Abase + (size_t)rrow[i] * K + k0 + scol[i],
                        &Ash[(i * 256 + wid * 64) * 8]);
            GLOAD_LDS16(Wbase + (size_t)rrow[i] * K + k0 + scol[i],
                        &Bsh[(i * 256 + wid * 64) * 8]);
        }
        __syncthreads();                 // drains vmcnt; tile visible
        #pragma unroll
        for (int kk = 0; kk < 2; ++kk) {
            short8 af[4], bf[4];
            const int slotg = (kk << 2) + (l >> 4);
            #pragma unroll
            for (int mi = 0; mi < 4; ++mi) {
                const int row = wr * 64 + mi * 16 + (l & 15);
                af[mi] = *(const short8*)&Ash[row * 64 + ((slotg ^ (row & 7)) << 3)];
            }
            #pragma unroll
            for (int ni = 0; ni < 4; ++ni) {
                const int row = wc * 64 + ni * 16 + (l & 15);
                bf[ni] = *(const short8*)&Bsh[row * 64 + ((slotg ^ (row & 7)) << 3)];
            }
            #pragma unroll
            for (int mi = 0; mi < 4; ++mi)
                #pragma unroll
                for (int ni = 0; ni < 4; ++ni)
                    acc[mi][ni] = __builtin_amdgcn_mfma_f32_16x16x32_bf16(
                        af[mi], bf[ni], acc[mi][ni], 0, 0, 0);
        }
    }

    #pragma unroll
    for (int ni = 0; ni < 4; ++ni) {
        const int col = n0 + wc * 64 + ni * 16 + (l & 15);
        const float bv = bias[col];
        if (QKV) {
            const int part = col >> 10;
            const int h = (col >> 6) & 15;
            const int e = col & 63;
            short* __restrict__ dst = part == 0 ? qo : (part == 1 ? ko : vo);
            #pragma unroll
            for (int mi = 0; mi < 4; ++mi) {
                #pragma unroll
                for (int r = 0; r < 4; ++r) {
                    int row = m0 + wr * 64 + mi * 16 + ((l >> 4) << 2) + r;
                    int b = row >> 11, s = row & (S_LEN - 1);
                    dst[((size_t)(b * NHEAD + h) * S_LEN + s) * HD + e] =
                        (short)f2bf(acc[mi][ni][r] + bv);
                }
            }
        } else {
            #pragma unroll
            for (int mi = 0; mi < 4; ++mi) {
                #pragma unroll
                for (int r = 0; r < 4; ++r) {
                    int row = m0 + wr * 64 + mi * 16 + ((l >> 4) << 2) + r;
                    C[(size_t)row * N + col] = acc[mi][ni][r] + bv;
                }
            }
        }
    }
}

// ---------------------------------------------------------------------------
// V transpose: [bh][s][64] -> [bh][64][s], 64x64 LDS tiles (unchanged r7).
// ---------------------------------------------------------------------------
__global__ __launch_bounds__(256) void transpose_v(
    const short* __restrict__ vin, short* __restrict__ vout)
{
    __shared__ short t[64][72];
    const int tid = threadIdx.x;
    const int bh = blockIdx.x >> 5;
    const int s0 = (blockIdx.x & 31) << 6;
    const size_t ibase = (size_t)bh * S_LEN * HD;
    const size_t obase = (size_t)bh * HD * S_LEN;
    const int r = tid >> 3, c8 = (tid & 7) << 3;

    #pragma unroll
    for (int p = 0; p < 2; ++p) {
        short8 v = *(const short8*)&vin[ibase + (size_t)(s0 + r + p * 32) * HD + c8];
        *(short8*)&t[r + p * 32][c8] = v;
    }
    __syncthreads();
    #pragma unroll
    for (int p = 0; p < 2; ++p) {
        const int e = r + p * 32;
        short8 o;
        #pragma unroll
        for (int i = 0; i < 8; ++i) o[i] = t[c8 + i][e];
        *(short8*)&vout[obase + (size_t)e * S_LEN + s0 + c8] = o;
    }
}

// ---------------------------------------------------------------------------
// MFMA flash attention v3 (r7-validated structure + gload_lds staging +
// exact skip-rescale).  Block = 64 q-rows; LPT qt = 31 - bid/32.
// Swapped QK^T: mfma(K,Q) -> lane owns q-row c15, 16 S-values in registers.
// P stays in registers for PV (shared k-bijection on P and V, HW-validated).
// K/V staged via global_load_lds: linear LDS dest, pre-swizzled global
// source (slot ^= row&7); reads XOR the same involution (unchanged).
// Skip-rescale: when __all(mx <= mr) the alpha-rescale is identity -> skip
// (bit-exact, saves 17 VALU ops/tile on converged rows).
// ---------------------------------------------------------------------------
__global__ __launch_bounds__(256) void flash_attn_mfma(
    const short* __restrict__ q, const short* __restrict__ k,
    const short* __restrict__ vt, short* __restrict__ yb)
{
    __shared__ __align__(16) short Ks[64 * 64];   // [key][kdim] swizzled
    __shared__ __align__(16) short Vs[64 * 64];   // [e][key]   swizzled

    const int tid = threadIdx.x;
    const int l = tid & 63;
    const int w = tid >> 6;
    const int h4 = l >> 4;
    const int c15 = l & 15;
    const int bid = blockIdx.x;
    const int qt = 31 - (bid >> 5);      // longest-first (LPT)
    const int bh = bid & 31;
    const int q0 = qt << 6;
    const int myq = q0 + (w << 4) + c15;

    const size_t kbase = (size_t)bh * S_LEN * HD;   // q,k: [bh][s][e]
    const size_t vbase = (size_t)bh * HD * S_LEN;   // vt:  [bh][e][s]

    short8 qf[2];
    {
        const short* qrow = q + kbase + (size_t)myq * HD;
        qf[0] = *(const short8*)(qrow + (h4 << 3));
        qf[1] = *(const short8*)(qrow + 32 + (h4 << 3));
    }

    f32x4 accO[4];   // O[q=c15][e = et*16 + h4*4 + r]
    #pragma unroll
    for (int i = 0; i < 4; ++i) accO[i] = (f32x4)0.0f;
    float mr = -1e30f, lr = 0.0f;

    // staging: chunk = p*256+tid -> row=chunk>>3, slotL=chunk&7 (linear dest)
    const int sr = tid >> 3, slotL = tid & 7;

    const int ntiles = qt + 1;
    for (int t = 0; t < ntiles; ++t) {
        const int kn = t << 6;
        __syncthreads();                 // prev compute done reading LDS
        #pragma unroll
        for (int p = 0; p < 2; ++p) {
            const int row = sr + p * 32;
            const int ss = (slotL ^ (row & 7)) << 3;   // pre-swizzled source
            GLOAD_LDS16(k + kbase + (size_t)(kn + row) * HD + ss,
                        &Ks[(p * 256 + w * 64) * 8]);
            GLOAD_LDS16(vt + vbase + (size_t)row * S_LEN + kn + ss,
                        &Vs[(p * 256 + w * 64) * 8]);
        }
        __syncthreads();                 // drains vmcnt; tile visible

        // ---- S^T = K Q^T : lane holds S[q=c15][key = nt*16 + h4*4 + r]
        f32x4 sacc[4];
        #pragma unroll
        for (int nt = 0; nt < 4; ++nt) sacc[nt] = (f32x4)0.0f;
        #pragma unroll
        for (int c = 0; c < 2; ++c) {
            const int kof = (c << 5) + (h4 << 3);
            #pragma unroll
            for (int nt = 0; nt < 4; ++nt) {
                const int keyrow = nt * 16 + c15;
                const short8 kf = *(const short8*)&Ks[keyrow * 64 + (kof ^ ((keyrow & 7) << 3))];
                sacc[nt] = __builtin_amdgcn_mfma_f32_16x16x32_bf16(kf, qf[c], sacc[nt], 0, 0, 0);
            }
        }

        // ---- scale + causal mask (diag tile only)
        float p16[16];
        const bool diag = (t == qt);
        #pragma unroll
        for (int nt = 0; nt < 4; ++nt)
            #pragma unroll
            for (int r = 0; r < 4; ++r) {
                float v = sacc[nt][r] * 0.125f;   // 1/sqrt(64)
                if (diag && (nt * 16 + (h4 << 2) + r > (w << 4) + c15))
                    v = -1e30f;
                p16[nt * 4 + r] = v;
            }

        // ---- online softmax, lane-local q-row; reduce across h4 groups
        float mx = p16[0];
        #pragma unroll
        for (int i = 1; i < 16; ++i) mx = fmaxf(mx, p16[i]);
        mx = fmaxf(mx, __shfl_xor(mx, 16, 64));
        mx = fmaxf(mx, __shfl_xor(mx, 32, 64));
        if (!__all(mx <= mr)) {          // exact: skipped iff alpha==1 wave-wide
            const float mnew = fmaxf(mr, mx);
            const float alpha = __expf(mr - mnew);
            mr = mnew;
            lr *= alpha;
            #pragma unroll
            for (int et = 0; et < 4; ++et) accO[et] *= alpha;
        }
        float rs = 0.0f;
        #pragma unroll
        for (int i = 0; i < 16; ++i) {
            p16[i] = __expf(p16[i] - mr);
            rs += p16[i];
        }
        rs += __shfl_xor(rs, 16, 64);
        rs += __shfl_xor(rs, 32, 64);
        lr += rs;

        // ---- P bf16 B-fragments, in registers (k-order g_c)
        short8 pb[2];
        #pragma unroll
        for (int c = 0; c < 2; ++c)
            #pragma unroll
            for (int i = 0; i < 8; ++i)
                pb[c][i] = (short)f2bf(p16[8 * c + i]);

        // ---- O += V^T x P : A = V^T rows e (2x b64 per frag), B = P regs
        #pragma unroll
        for (int c = 0; c < 2; ++c) {
            const int ch = (c << 2) + (h4 >> 1);
            const int halfo = (h4 & 1) << 2;
            #pragma unroll
            for (int et = 0; et < 4; ++et) {
                const int e = (et << 4) + c15;
                const int rb = e << 6;
                const int sw = e & 7;
                const short4_t va = *(const short4_t*)&Vs[rb + ((ch ^ sw) << 3) + halfo];
                const short4_t vb = *(const short4_t*)&Vs[rb + (((ch + 2) ^ sw) << 3) + halfo];
                const short8 vf = {va[0], va[1], va[2], va[3], vb[0], vb[1], vb[2], vb[3]};
                accO[et] = __builtin_amdgcn_mfma_f32_16x16x32_bf16(vf, pb[c], accO[et], 0, 0, 0);
            }
        }
    }

    // ---- epilogue: normalize (lane-local l), write bf16 y [B,S,D]
    const int bq = bh >> 4, hh = bh & 15;
    const float inv = 1.0f / lr;
    short* orow = yb + ((size_t)bq * S_LEN + myq) * DMODEL + hh * HD;
    #pragma unroll
    for (int et = 0; et < 4; ++et) {
        short4_t o;
        #pragma unroll
        for (int r = 0; r < 4; ++r) o[r] = (short)f2bf(accO[et][r] * inv);
        *(short4_t*)&orow[(et << 4) + (h4 << 2)] = o;
    }
}

// ---------------------------------------------------------------------------
// Workspace (46 MB):
//   [ 0, 8M) q bf16 [B,H,S,hd]     [ 8,16M) k bf16     [16,24M) v bf16
//   [24,32M) v^T bf16 [B,H,hd,S]
//   [32,40M) xb (cast->gemm1) / yb (attn->gemm2)   — disjoint in time
//   [40,46M) wab (cast->gemm1) / wpb (cast->gemm2) — disjoint in time
// ---------------------------------------------------------------------------
extern "C" void kernel_launch(void* const* d_in, const int* in_sizes, int n_in,
                              void* d_out, int out_size, void* d_ws, size_t ws_size,
                              hipStream_t stream) {
    const float* x      = (const float*)d_in[0];
    const float* w_attn = (const float*)d_in[1];
    const float* b_attn = (const float*)d_in[2];
    const float* w_proj = (const float*)d_in[3];
    const float* b_proj = (const float*)d_in[4];
    float* out = (float*)d_out;

    const int B = 2;
    const int M = B * S_LEN;
    const size_t x_elems  = (size_t)M * DMODEL;
    const size_t wa_elems = (size_t)3 * DMODEL * DMODEL;
    const size_t wp_elems = (size_t)DMODEL * DMODEL;

    char* wsb = (char*)d_ws;
    short* qw  = (short*)(wsb);
    short* kw  = (short*)(wsb + (8u << 20));
    short* vw  = (short*)(wsb + (16u << 20));
    short* vtw = (short*)(wsb + (24u << 20));
    short* xb  = (short*)(wsb + (32u << 20));
    short* yb  = (short*)(wsb + (32u << 20));
    short* wab = (short*)(wsb + (40u << 20));
    short* wpb = (short*)(wsb + (40u << 20));

    cast_f32_bf16<<<dim3((int)(x_elems  / 8 / 256)), 256, 0, stream>>>(x, xb, (int)(x_elems / 8));
    cast_f32_bf16<<<dim3((int)(wa_elems / 8 / 256)), 256, 0, stream>>>(w_attn, wab, (int)(wa_elems / 8));

    dim3 g1(3 * DMODEL / 128, M / 128);
    gemm_mfma<true><<<g1, 256, 0, stream>>>(xb, wab, b_attn, nullptr,
                                            3 * DMODEL, DMODEL, qw, kw, vw);

    cast_f32_bf16<<<dim3((int)(wp_elems / 8 / 256)), 256, 0, stream>>>(w_proj, wpb, (int)(wp_elems / 8));
    transpose_v<<<dim3(2 * NHEAD * (S_LEN / 64)), 256, 0, stream>>>(vw, vtw);

    flash_attn_mfma<<<dim3(2 * NHEAD * (S_LEN / 64)), 256, 0, stream>>>(qw, kw, vtw, yb);

    dim3 g3(DMODEL / 128, M / 128);
    gemm_mfma<false><<<g3, 256, 0, stream>>>(yb, wpb, b_proj, out,
                                             DMODEL, DMODEL,
                                             nullptr, nullptr, nullptr);
}

// Round 11
// 196.546 us; speedup vs baseline: 1.0374x; 1.0374x over previous
//
#include <hip/hip_runtime.h>
#include <hip/hip_bf16.h>

#define S_LEN 2048
#define DMODEL 1024
#define NHEAD 16
#define HD 64

typedef short short8 __attribute__((ext_vector_type(8)));
typedef short short4_t __attribute__((ext_vector_type(4)));
typedef float f32x4 __attribute__((ext_vector_type(4)));

// async global->LDS, 16B per lane; dest = wave-uniform base + lane*16
#define GLOAD_LDS16(gp, lp)                                        \
    __builtin_amdgcn_global_load_lds(                              \
        (__attribute__((address_space(1))) void*)(gp),             \
        (__attribute__((address_space(3))) void*)(lp), 16, 0, 0)

// fp32 -> bf16 (RNE) bit-level
__device__ inline unsigned short f2bf(float f) {
    union { float f; unsigned int u; } c;
    c.f = f;
    unsigned int r = c.u + 0x7fffu + ((c.u >> 16) & 1u);
    return (unsigned short)(r >> 16);
}

// ---------------------------------------------------------------------------
// Fused cast of all three fp32 inputs -> bf16 (one launch).
// Chunk map (8 elems/chunk): [0,524288) x | [524288,917504) w_attn |
// [917504,1048576) w_proj. Divergence only at 2 block boundaries.
// ---------------------------------------------------------------------------
__global__ __launch_bounds__(256) void cast3_f32_bf16(
    const float* __restrict__ x, const float* __restrict__ wa,
    const float* __restrict__ wp,
    short* __restrict__ xb, short* __restrict__ wab, short* __restrict__ wpb)
{
    const int i = blockIdx.x * 256 + threadIdx.x;
    const float* src;
    short* dst;
    if (i < 524288)      { src = x  + (size_t)i * 8;            dst = xb  + (size_t)i * 8; }
    else if (i < 917504) { src = wa + (size_t)(i - 524288) * 8; dst = wab + (size_t)(i - 524288) * 8; }
    else                 { src = wp + (size_t)(i - 917504) * 8; dst = wpb + (size_t)(i - 917504) * 8; }
    float4 a = ((const float4*)src)[0];
    float4 b = ((const float4*)src)[1];
    short8 o;
    o[0] = (short)f2bf(a.x); o[1] = (short)f2bf(a.y);
    o[2] = (short)f2bf(a.z); o[3] = (short)f2bf(a.w);
    o[4] = (short)f2bf(b.x); o[5] = (short)f2bf(b.y);
    o[6] = (short)f2bf(b.z); o[7] = (short)f2bf(b.w);
    *(short8*)dst = o;
}

// ---------------------------------------------------------------------------
// bf16 MFMA GEMM: C = A @ W^T + bias.  BM=BN=128, BK=64, 4 waves 2x2.
// r9: 2-phase double-buffered pipeline (T3-minimum): issue next K-tile's
// global_load_lds into buf^1 BEFORE computing buf; one __syncthreads (which
// drains vmcnt) per iteration -> HBM latency hides under 32 MFMA + ds_reads.
// LDS staging keeps the r8-validated pre-swizzled-source / swizzled-read
// involution (slot ^= row&7 on 16B slots; conflicts measured 0).
// C/D mapping (HW-verified): col=lane&15, row=(lane>>4)*4+reg.
// ---------------------------------------------------------------------------
template<bool QKV>
__global__ __launch_bounds__(256) void gemm_mfma(
    const short* __restrict__ A, const short* __restrict__ W,
    const float* __restrict__ bias, float* __restrict__ C,
    int N, int K,
    short* __restrict__ qo, short* __restrict__ ko, short* __restrict__ vo)
{
    __shared__ __align__(16) short Ash[2][128 * 64];   // 2 x 16 KB
    __shared__ __align__(16) short Bsh[2][128 * 64];

    const int tid = threadIdx.x;
    const int l = tid & 63;
    const int wid = tid >> 6;
    const int wr = wid >> 1, wc = wid & 1;
    const int n0 = blockIdx.x << 7, m0 = blockIdx.y << 7;

    const short* Abase = A + (size_t)m0 * K;
    const short* Wbase = W + (size_t)n0 * K;

    f32x4 acc[4][4];
    #pragma unroll
    for (int i = 0; i < 4; ++i)
        #pragma unroll
        for (int j = 0; j < 4; ++j)
            acc[i][j] = (f32x4)0.0f;

    // staging: chunk = i*256+tid -> dest row=chunk>>3, slot=chunk&7 (linear);
    // source slot pre-swizzled: (chunk&7) ^ (row&7)
    int rrow[4], scol[4];
    #pragma unroll
    for (int i = 0; i < 4; ++i) {
        int chunk = i * 256 + tid;
        rrow[i] = chunk >> 3;
        scol[i] = ((chunk & 7) ^ (rrow[i] & 7)) << 3;
    }

    auto stage = [&](int buf, int k0) {
        #pragma unroll
        for (int i = 0; i < 4; ++i) {
            GLOAD_LDS16(Abase + (size_t)rrow[i] * K + k0 + scol[i],
                        &Ash[buf][(i * 256 + wid * 64) * 8]);
            GLOAD_LDS16(Wbase + (size_t)rrow[i] * K + k0 + scol[i],
                        &Bsh[buf][(i * 256 + wid * 64) * 8]);
        }
    };

    auto compute = [&](int buf) {
        #pragma unroll
        for (int kk = 0; kk < 2; ++kk) {
            short8 af[4], bf[4];
            const int slotg = (kk << 2) + (l >> 4);
            #pragma unroll
            for (int mi = 0; mi < 4; ++mi) {
                const int row = wr * 64 + mi * 16 + (l & 15);
                af[mi] = *(const short8*)&Ash[buf][row * 64 + ((slotg ^ (row & 7)) << 3)];
            }
            #pragma unroll
            for (int ni = 0; ni < 4; ++ni) {
                const int row = wc * 64 + ni * 16 + (l & 15);
                bf[ni] = *(const short8*)&Bsh[buf][row * 64 + ((slotg ^ (row & 7)) << 3)];
            }
            #pragma unroll
            for (int mi = 0; mi < 4; ++mi)
                #pragma unroll
                for (int ni = 0; ni < 4; ++ni)
                    acc[mi][ni] = __builtin_amdgcn_mfma_f32_16x16x32_bf16(
                        af[mi], bf[ni], acc[mi][ni], 0, 0, 0);
        }
    };

    const int NT = K >> 6;
    stage(0, 0);
    __syncthreads();                     // prologue tile landed
    int cur = 0;
    for (int kt = 0; kt < NT; ++kt) {
        if (kt + 1 < NT) stage(cur ^ 1, (kt + 1) << 6);   // issue-early
        compute(cur);                                      // hides the loads
        __syncthreads();                 // drains vmcnt; next tile visible
        cur ^= 1;
    }

    #pragma unroll
    for (int ni = 0; ni < 4; ++ni) {
        const int col = n0 + wc * 64 + ni * 16 + (l & 15);
        const float bv = bias[col];
        if (QKV) {
            const int part = col >> 10;
            const int h = (col >> 6) & 15;
            const int e = col & 63;
            short* __restrict__ dst = part == 0 ? qo : (part == 1 ? ko : vo);
            #pragma unroll
            for (int mi = 0; mi < 4; ++mi) {
                #pragma unroll
                for (int r = 0; r < 4; ++r) {
                    int row = m0 + wr * 64 + mi * 16 + ((l >> 4) << 2) + r;
                    int b = row >> 11, s = row & (S_LEN - 1);
                    dst[((size_t)(b * NHEAD + h) * S_LEN + s) * HD + e] =
                        (short)f2bf(acc[mi][ni][r] + bv);
                }
            }
        } else {
            #pragma unroll
            for (int mi = 0; mi < 4; ++mi) {
                #pragma unroll
                for (int r = 0; r < 4; ++r) {
                    int row = m0 + wr * 64 + mi * 16 + ((l >> 4) << 2) + r;
                    C[(size_t)row * N + col] = acc[mi][ni][r] + bv;
                }
            }
        }
    }
}

// ---------------------------------------------------------------------------
// V transpose: [bh][s][64] -> [bh][64][s], 64x64 LDS tiles (unchanged r7).
// ---------------------------------------------------------------------------
__global__ __launch_bounds__(256) void transpose_v(
    const short* __restrict__ vin, short* __restrict__ vout)
{
    __shared__ short t[64][72];
    const int tid = threadIdx.x;
    const int bh = blockIdx.x >> 5;
    const int s0 = (blockIdx.x & 31) << 6;
    const size_t ibase = (size_t)bh * S_LEN * HD;
    const size_t obase = (size_t)bh * HD * S_LEN;
    const int r = tid >> 3, c8 = (tid & 7) << 3;

    #pragma unroll
    for (int p = 0; p < 2; ++p) {
        short8 v = *(const short8*)&vin[ibase + (size_t)(s0 + r + p * 32) * HD + c8];
        *(short8*)&t[r + p * 32][c8] = v;
    }
    __syncthreads();
    #pragma unroll
    for (int p = 0; p < 2; ++p) {
        const int e = r + p * 32;
        short8 o;
        #pragma unroll
        for (int i = 0; i < 8; ++i) o[i] = t[c8 + i][e];
        *(short8*)&vout[obase + (size_t)e * S_LEN + s0 + c8] = o;
    }
}

// ---------------------------------------------------------------------------
// MFMA flash attention v4 = r7/r8-validated structure + 2-phase K/V
// double-buffer (same pipeline as gemm). Block = 64 q-rows; LPT.
// Swapped QK^T: mfma(K,Q) -> lane owns q-row c15, 16 S in registers.
// P in registers for PV (shared k-bijection, HW-validated).
// Exact skip-rescale (bit-exact alpha==1 skip).
// ---------------------------------------------------------------------------
__global__ __launch_bounds__(256) void flash_attn_mfma(
    const short* __restrict__ q, const short* __restrict__ k,
    const short* __restrict__ vt, short* __restrict__ yb)
{
    __shared__ __align__(16) short Ks[2][64 * 64];   // [key][kdim] swizzled
    __shared__ __align__(16) short Vs[2][64 * 64];   // [e][key]   swizzled

    const int tid = threadIdx.x;
    const int l = tid & 63;
    const int w = tid >> 6;
    const int h4 = l >> 4;
    const int c15 = l & 15;
    const int bid = blockIdx.x;
    const int qt = 31 - (bid >> 5);      // longest-first (LPT)
    const int bh = bid & 31;
    const int q0 = qt << 6;
    const int myq = q0 + (w << 4) + c15;

    const size_t kbase = (size_t)bh * S_LEN * HD;   // q,k: [bh][s][e]
    const size_t vbase = (size_t)bh * HD * S_LEN;   // vt:  [bh][e][s]

    short8 qf[2];
    {
        const short* qrow = q + kbase + (size_t)myq * HD;
        qf[0] = *(const short8*)(qrow + (h4 << 3));
        qf[1] = *(const short8*)(qrow + 32 + (h4 << 3));
    }

    f32x4 accO[4];   // O[q=c15][e = et*16 + h4*4 + r]
    #pragma unroll
    for (int i = 0; i < 4; ++i) accO[i] = (f32x4)0.0f;
    float mr = -1e30f, lr = 0.0f;

    const int sr = tid >> 3, slotL = tid & 7;

    auto stageKV = [&](int buf, int kn) {
        #pragma unroll
        for (int p = 0; p < 2; ++p) {
            const int row = sr + p * 32;
            const int ss = (slotL ^ (row & 7)) << 3;   // pre-swizzled source
            GLOAD_LDS16(k + kbase + (size_t)(kn + row) * HD + ss,
                        &Ks[buf][(p * 256 + w * 64) * 8]);
            GLOAD_LDS16(vt + vbase + (size_t)row * S_LEN + kn + ss,
                        &Vs[buf][(p * 256 + w * 64) * 8]);
        }
    };

    const int ntiles = qt + 1;
    stageKV(0, 0);
    __syncthreads();                     // prologue tile landed
    int cur = 0;

    for (int t = 0; t < ntiles; ++t) {
        if (t + 1 < ntiles) stageKV(cur ^ 1, (t + 1) << 6);   // issue-early

        // ---- S^T = K Q^T : lane holds S[q=c15][key = nt*16 + h4*4 + r]
        f32x4 sacc[4];
        #pragma unroll
        for (int nt = 0; nt < 4; ++nt) sacc[nt] = (f32x4)0.0f;
        #pragma unroll
        for (int c = 0; c < 2; ++c) {
            const int kof = (c << 5) + (h4 << 3);
            #pragma unroll
            for (int nt = 0; nt < 4; ++nt) {
                const int keyrow = nt * 16 + c15;
                const short8 kf = *(const short8*)&Ks[cur][keyrow * 64 + (kof ^ ((keyrow & 7) << 3))];
                sacc[nt] = __builtin_amdgcn_mfma_f32_16x16x32_bf16(kf, qf[c], sacc[nt], 0, 0, 0);
            }
        }

        // ---- scale + causal mask (diag tile only)
        float p16[16];
        const bool diag = (t == qt);
        #pragma unroll
        for (int nt = 0; nt < 4; ++nt)
            #pragma unroll
            for (int r = 0; r < 4; ++r) {
                float v = sacc[nt][r] * 0.125f;   // 1/sqrt(64)
                if (diag && (nt * 16 + (h4 << 2) + r > (w << 4) + c15))
                    v = -1e30f;
                p16[nt * 4 + r] = v;
            }

        // ---- online softmax, lane-local q-row; reduce across h4 groups
        float mx = p16[0];
        #pragma unroll
        for (int i = 1; i < 16; ++i) mx = fmaxf(mx, p16[i]);
        mx = fmaxf(mx, __shfl_xor(mx, 16, 64));
        mx = fmaxf(mx, __shfl_xor(mx, 32, 64));
        if (!__all(mx <= mr)) {          // exact: skipped iff alpha==1 wave-wide
            const float mnew = fmaxf(mr, mx);
            const float alpha = __expf(mr - mnew);
            mr = mnew;
            lr *= alpha;
            #pragma unroll
            for (int et = 0; et < 4; ++et) accO[et] *= alpha;
        }
        float rs = 0.0f;
        #pragma unroll
        for (int i = 0; i < 16; ++i) {
            p16[i] = __expf(p16[i] - mr);
            rs += p16[i];
        }
        rs += __shfl_xor(rs, 16, 64);
        rs += __shfl_xor(rs, 32, 64);
        lr += rs;

        // ---- P bf16 B-fragments, in registers (k-order g_c)
        short8 pb[2];
        #pragma unroll
        for (int c = 0; c < 2; ++c)
            #pragma unroll
            for (int i = 0; i < 8; ++i)
                pb[c][i] = (short)f2bf(p16[8 * c + i]);

        // ---- O += V^T x P : A = V^T rows e (2x b64 per frag), B = P regs
        #pragma unroll
        for (int c = 0; c < 2; ++c) {
            const int ch = (c << 2) + (h4 >> 1);
            const int halfo = (h4 & 1) << 2;
            #pragma unroll
            for (int et = 0; et < 4; ++et) {
                const int e = (et << 4) + c15;
                const int rb = e << 6;
                const int sw = e & 7;
                const short4_t va = *(const short4_t*)&Vs[cur][rb + ((ch ^ sw) << 3) + halfo];
                const short4_t vb = *(const short4_t*)&Vs[cur][rb + (((ch + 2) ^ sw) << 3) + halfo];
                const short8 vf = {va[0], va[1], va[2], va[3], vb[0], vb[1], vb[2], vb[3]};
                accO[et] = __builtin_amdgcn_mfma_f32_16x16x32_bf16(vf, pb[c], accO[et], 0, 0, 0);
            }
        }

        __syncthreads();                 // drains vmcnt; next tile visible
        cur ^= 1;
    }

    // ---- epilogue: normalize (lane-local l), write bf16 y [B,S,D]
    const int bq = bh >> 4, hh = bh & 15;
    const float inv = 1.0f / lr;
    short* orow = yb + ((size_t)bq * S_LEN + myq) * DMODEL + hh * HD;
    #pragma unroll
    for (int et = 0; et < 4; ++et) {
        short4_t o;
        #pragma unroll
        for (int r = 0; r < 4; ++r) o[r] = (short)f2bf(accO[et][r] * inv);
        *(short4_t*)&orow[(et << 4) + (h4 << 2)] = o;
    }
}

// ---------------------------------------------------------------------------
// Workspace (48 MB):
//   [ 0, 8M) q bf16 [B,H,S,hd]   [ 8,16M) k bf16   [16,24M) v bf16
//   [24,32M) v^T bf16 [B,H,hd,S]
//   [32,40M) xb (cast->gemm1) / yb (attn->gemm2)  — disjoint in time
//   [40,46M) wab (cast->gemm1)
//   [46,48M) wpb (cast->gemm2)  — own slot now (all casts fused, pre-gemm1)
// ---------------------------------------------------------------------------
extern "C" void kernel_launch(void* const* d_in, const int* in_sizes, int n_in,
                              void* d_out, int out_size, void* d_ws, size_t ws_size,
                              hipStream_t stream) {
    const float* x      = (const float*)d_in[0];
    const float* w_attn = (const float*)d_in[1];
    const float* b_attn = (const float*)d_in[2];
    const float* w_proj = (const float*)d_in[3];
    const float* b_proj = (const float*)d_in[4];
    float* out = (float*)d_out;

    const int B = 2;
    const int M = B * S_LEN;

    char* wsb = (char*)d_ws;
    short* qw  = (short*)(wsb);
    short* kw  = (short*)(wsb + (8u << 20));
    short* vw  = (short*)(wsb + (16u << 20));
    short* vtw = (short*)(wsb + (24u << 20));
    short* xb  = (short*)(wsb + (32u << 20));
    short* yb  = (short*)(wsb + (32u << 20));
    short* wab = (short*)(wsb + (40u << 20));
    short* wpb = (short*)(wsb + (46u << 20));

    cast3_f32_bf16<<<dim3(4096), 256, 0, stream>>>(x, w_attn, w_proj, xb, wab, wpb);

    dim3 g1(3 * DMODEL / 128, M / 128);
    gemm_mfma<true><<<g1, 256, 0, stream>>>(xb, wab, b_attn, nullptr,
                                            3 * DMODEL, DMODEL, qw, kw, vw);

    transpose_v<<<dim3(2 * NHEAD * (S_LEN / 64)), 256, 0, stream>>>(vw, vtw);

    flash_attn_mfma<<<dim3(2 * NHEAD * (S_LEN / 64)), 256, 0, stream>>>(qw, kw, vtw, yb);

    dim3 g3(DMODEL / 128, M / 128);
    gemm_mfma<false><<<g3, 256, 0, stream>>>(yb, wpb, b_proj, out,
                                             DMODEL, DMODEL,
                                             nullptr, nullptr, nullptr);
}

// Round 13
// 191.116 us; speedup vs baseline: 1.0669x; 1.0284x over previous
//
#include <hip/hip_runtime.h>
#include <hip/hip_bf16.h>

#define S_LEN 2048
#define DMODEL 1024
#define NHEAD 16
#define HD 64

typedef short short8 __attribute__((ext_vector_type(8)));
typedef short short4_t __attribute__((ext_vector_type(4)));
typedef float f32x4 __attribute__((ext_vector_type(4)));

// async global->LDS, 16B per lane; dest = wave-uniform base + lane*16
#define GLOAD_LDS16(gp, lp)                                        \
    __builtin_amdgcn_global_load_lds(                              \
        (__attribute__((address_space(1))) void*)(gp),             \
        (__attribute__((address_space(3))) void*)(lp), 16, 0, 0)

// fp32 -> bf16 (RNE) bit-level
__device__ inline unsigned short f2bf(float f) {
    union { float f; unsigned int u; } c;
    c.f = f;
    unsigned int r = c.u + 0x7fffu + ((c.u >> 16) & 1u);
    return (unsigned short)(r >> 16);
}

// ---------------------------------------------------------------------------
// Fused cast of all three fp32 inputs -> bf16 (one launch). (r9, unchanged)
// ---------------------------------------------------------------------------
__global__ __launch_bounds__(256) void cast3_f32_bf16(
    const float* __restrict__ x, const float* __restrict__ wa,
    const float* __restrict__ wp,
    short* __restrict__ xb, short* __restrict__ wab, short* __restrict__ wpb)
{
    const int i = blockIdx.x * 256 + threadIdx.x;
    const float* src;
    short* dst;
    if (i < 524288)      { src = x  + (size_t)i * 8;            dst = xb  + (size_t)i * 8; }
    else if (i < 917504) { src = wa + (size_t)(i - 524288) * 8; dst = wab + (size_t)(i - 524288) * 8; }
    else                 { src = wp + (size_t)(i - 917504) * 8; dst = wpb + (size_t)(i - 917504) * 8; }
    float4 a = ((const float4*)src)[0];
    float4 b = ((const float4*)src)[1];
    short8 o;
    o[0] = (short)f2bf(a.x); o[1] = (short)f2bf(a.y);
    o[2] = (short)f2bf(a.z); o[3] = (short)f2bf(a.w);
    o[4] = (short)f2bf(b.x); o[5] = (short)f2bf(b.y);
    o[6] = (short)f2bf(b.z); o[7] = (short)f2bf(b.w);
    *(short8*)dst = o;
}

// ---------------------------------------------------------------------------
// bf16 MFMA GEMM: C = A @ W^T + bias.  BM=BN=128, BK=64, 4 waves 2x2.
// r11-validated 2-phase gload_lds pipeline (bank conflicts measured 0).
// r12: SWAPPED operand order mfma(bf, af) -> lane holds C[row = ...+c15]
// [cols = colb + 0..3] (one row x 4 consecutive cols), by the HW-validated
// symmetric fragment mapping. Epilogue: 16 coalesced 8B/16B stores per
// thread instead of 64 scalar stores. Numerically identical.
// ---------------------------------------------------------------------------
template<bool QKV>
__global__ __launch_bounds__(256) void gemm_mfma(
    const short* __restrict__ A, const short* __restrict__ W,
    const float* __restrict__ bias, float* __restrict__ C,
    int N, int K,
    short* __restrict__ qo, short* __restrict__ ko, short* __restrict__ vo)
{
    __shared__ __align__(16) short Ash[2][128 * 64];
    __shared__ __align__(16) short Bsh[2][128 * 64];

    const int tid = threadIdx.x;
    const int l = tid & 63;
    const int wid = tid >> 6;
    const int wr = wid >> 1, wc = wid & 1;
    const int c15 = l & 15, h4 = l >> 4;
    const int n0 = blockIdx.x << 7, m0 = blockIdx.y << 7;

    const short* Abase = A + (size_t)m0 * K;
    const short* Wbase = W + (size_t)n0 * K;

    f32x4 acc[4][4];
    #pragma unroll
    for (int i = 0; i < 4; ++i)
        #pragma unroll
        for (int j = 0; j < 4; ++j)
            acc[i][j] = (f32x4)0.0f;

    int rrow[4], scol[4];
    #pragma unroll
    for (int i = 0; i < 4; ++i) {
        int chunk = i * 256 + tid;
        rrow[i] = chunk >> 3;
        scol[i] = ((chunk & 7) ^ (rrow[i] & 7)) << 3;   // pre-swizzled source
    }

    auto stage = [&](int buf, int k0) {
        #pragma unroll
        for (int i = 0; i < 4; ++i) {
            GLOAD_LDS16(Abase + (size_t)rrow[i] * K + k0 + scol[i],
                        &Ash[buf][(i * 256 + wid * 64) * 8]);
            GLOAD_LDS16(Wbase + (size_t)rrow[i] * K + k0 + scol[i],
                        &Bsh[buf][(i * 256 + wid * 64) * 8]);
        }
    };

    auto compute = [&](int buf) {
        #pragma unroll
        for (int kk = 0; kk < 2; ++kk) {
            short8 af[4], bf[4];
            const int slotg = (kk << 2) + h4;
            #pragma unroll
            for (int mi = 0; mi < 4; ++mi) {
                const int row = wr * 64 + mi * 16 + c15;
                af[mi] = *(const short8*)&Ash[buf][row * 64 + ((slotg ^ (row & 7)) << 3)];
            }
            #pragma unroll
            for (int ni = 0; ni < 4; ++ni) {
                const int row = wc * 64 + ni * 16 + c15;
                bf[ni] = *(const short8*)&Bsh[buf][row * 64 + ((slotg ^ (row & 7)) << 3)];
            }
            #pragma unroll
            for (int mi = 0; mi < 4; ++mi)
                #pragma unroll
                for (int ni = 0; ni < 4; ++ni)
                    acc[mi][ni] = __builtin_amdgcn_mfma_f32_16x16x32_bf16(
                        bf[ni], af[mi], acc[mi][ni], 0, 0, 0);   // swapped
        }
    };

    const int NT = K >> 6;
    stage(0, 0);
    __syncthreads();
    int cur = 0;
    for (int kt = 0; kt < NT; ++kt) {
        if (kt + 1 < NT) stage(cur ^ 1, (kt + 1) << 6);
        compute(cur);
        __syncthreads();
        cur ^= 1;
    }

    // epilogue: lane holds C[row][colb..colb+3]
    #pragma unroll
    for (int ni = 0; ni < 4; ++ni) {
        const int colb = n0 + wc * 64 + ni * 16 + (h4 << 2);
        const float4 b4 = *(const float4*)&bias[colb];
        if (QKV) {
            const int part = colb >> 10;
            const int h = (colb >> 6) & 15;
            const int e = colb & 63;
            short* __restrict__ dst = part == 0 ? qo : (part == 1 ? ko : vo);
            #pragma unroll
            for (int mi = 0; mi < 4; ++mi) {
                const int row = m0 + wr * 64 + mi * 16 + c15;
                const int b = row >> 11, s = row & (S_LEN - 1);
                short4_t o;
                o[0] = (short)f2bf(acc[mi][ni][0] + b4.x);
                o[1] = (short)f2bf(acc[mi][ni][1] + b4.y);
                o[2] = (short)f2bf(acc[mi][ni][2] + b4.z);
                o[3] = (short)f2bf(acc[mi][ni][3] + b4.w);
                *(short4_t*)&dst[((size_t)(b * NHEAD + h) * S_LEN + s) * HD + e] = o;
            }
        } else {
            #pragma unroll
            for (int mi = 0; mi < 4; ++mi) {
                const int row = m0 + wr * 64 + mi * 16 + c15;
                float4 o;
                o.x = acc[mi][ni][0] + b4.x;
                o.y = acc[mi][ni][1] + b4.y;
                o.z = acc[mi][ni][2] + b4.z;
                o.w = acc[mi][ni][3] + b4.w;
                *(float4*)&C[(size_t)row * N + colb] = o;
            }
        }
    }
}

// ---------------------------------------------------------------------------
// V transpose + PV-fragment reorder: [bh][s][64] -> [bh][64][s'] where each
// 64-key window is permuted into fragment order: position 8f+j holds key
// g(f,j) = 32*(f>>2) + 16*(j>>2) + 4*(f&3) + (j&3)  (the PV k-bijection).
// pos(kappa) = b5*32 + b3*16 + b2*8 + b4*4 + b1*2 + b0.
// This makes the attention V-read ONE b128 per fragment (K-read pattern,
// measured 0 conflicts) instead of split b64s (4.3M conflicts in r7/r11).
// ---------------------------------------------------------------------------
__global__ __launch_bounds__(256) void transpose_v(
    const short* __restrict__ vin, short* __restrict__ vout)
{
    __shared__ short t[64][72];
    const int tid = threadIdx.x;
    const int bh = blockIdx.x >> 5;
    const int s0 = (blockIdx.x & 31) << 6;
    const size_t ibase = (size_t)bh * S_LEN * HD;
    const size_t obase = (size_t)bh * HD * S_LEN;
    const int r = tid >> 3, c8 = (tid & 7) << 3;

    #pragma unroll
    for (int p = 0; p < 2; ++p) {
        short8 v = *(const short8*)&vin[ibase + (size_t)(s0 + r + p * 32) * HD + c8];
        *(short8*)&t[r + p * 32][c8] = v;
    }
    __syncthreads();
    // kappa = c8 + i; i<4 -> P0+i, i>=4 -> P0+8+(i-4)
    const int P0 = (c8 & 32) | ((c8 & 8) << 1) | ((c8 & 16) >> 2);
    #pragma unroll
    for (int p = 0; p < 2; ++p) {
        const int e = r + p * 32;
        short4_t lo, hi;
        #pragma unroll
        for (int i = 0; i < 4; ++i) { lo[i] = t[c8 + i][e]; hi[i] = t[c8 + 4 + i][e]; }
        *(short4_t*)&vout[obase + (size_t)e * S_LEN + s0 + P0] = lo;
        *(short4_t*)&vout[obase + (size_t)e * S_LEN + s0 + P0 + 8] = hi;
    }
}

// ---------------------------------------------------------------------------
// MFMA flash attention v5: r7-measured-best staging (reg-prefetch +
// swizzled ds_write_b128, single buffer, 2 barriers/tile — 52us vs 57 for
// gload_lds variants) + fragment-ordered V (single b128 per PV fragment)
// + LPT + exact skip-rescale. Swapped QK^T, P in registers (unchanged).
// ---------------------------------------------------------------------------
__global__ __launch_bounds__(256) void flash_attn_mfma(
    const short* __restrict__ q, const short* __restrict__ k,
    const short* __restrict__ vt, short* __restrict__ yb)
{
    __shared__ __align__(16) short Ks[64 * 64];   // [key][kdim] swizzled
    __shared__ __align__(16) short Vs[64 * 64];   // [e][frag]  swizzled

    const int tid = threadIdx.x;
    const int l = tid & 63;
    const int w = tid >> 6;
    const int h4 = l >> 4;
    const int c15 = l & 15;
    const int bid = blockIdx.x;
    const int qt = 31 - (bid >> 5);      // longest-first (LPT)
    const int bh = bid & 31;
    const int q0 = qt << 6;
    const int myq = q0 + (w << 4) + c15;

    const size_t kbase = (size_t)bh * S_LEN * HD;   // q,k: [bh][s][e]
    const size_t vbase = (size_t)bh * HD * S_LEN;   // vt:  [bh][e][s'] frag-ordered

    short8 qf[2];
    {
        const short* qrow = q + kbase + (size_t)myq * HD;
        qf[0] = *(const short8*)(qrow + (h4 << 3));
        qf[1] = *(const short8*)(qrow + 32 + (h4 << 3));
    }

    f32x4 accO[4];   // O[q=c15][e = et*16 + h4*4 + r]
    #pragma unroll
    for (int i = 0; i < 4; ++i) accO[i] = (f32x4)0.0f;
    float mr = -1e30f, lr = 0.0f;

    const int srow0 = tid >> 3, scol = tid & 7;
    short8 kreg[2], vreg[2];
    #pragma unroll
    for (int p = 0; p < 2; ++p) {
        kreg[p] = *(const short8*)(k + kbase + (size_t)(srow0 + p * 32) * HD + scol * 8);
        vreg[p] = *(const short8*)(vt + vbase + (size_t)(srow0 + p * 32) * S_LEN + scol * 8);
    }

    const int ntiles = qt + 1;
    for (int t = 0; t < ntiles; ++t) {
        __syncthreads();            // previous tile's LDS reads complete
        #pragma unroll
        for (int p = 0; p < 2; ++p) {
            const int row = srow0 + p * 32;
            const int sc = (scol ^ (row & 7)) << 3;
            *(short8*)&Ks[row * 64 + sc] = kreg[p];
            *(short8*)&Vs[row * 64 + sc] = vreg[p];
        }
        __syncthreads();            // tile visible to all waves
        if (t + 1 < ntiles) {
            const int kn = (t + 1) << 6;
            #pragma unroll
            for (int p = 0; p < 2; ++p) {
                kreg[p] = *(const short8*)(k + kbase + (size_t)(kn + srow0 + p * 32) * HD + scol * 8);
                vreg[p] = *(const short8*)(vt + vbase + (size_t)(srow0 + p * 32) * S_LEN + kn + scol * 8);
            }
        }

        // ---- S^T = K Q^T : lane holds S[q=c15][key = nt*16 + h4*4 + r]
        f32x4 sacc[4];
        #pragma unroll
        for (int nt = 0; nt < 4; ++nt) sacc[nt] = (f32x4)0.0f;
        #pragma unroll
        for (int c = 0; c < 2; ++c) {
            const int kof = (c << 5) + (h4 << 3);
            #pragma unroll
            for (int nt = 0; nt < 4; ++nt) {
                const int keyrow = nt * 16 + c15;
                const short8 kf = *(const short8*)&Ks[keyrow * 64 + (kof ^ ((keyrow & 7) << 3))];
                sacc[nt] = __builtin_amdgcn_mfma_f32_16x16x32_bf16(kf, qf[c], sacc[nt], 0, 0, 0);
            }
        }

        // ---- scale + causal mask (diag tile only)
        float p16[16];
        const bool diag = (t == qt);
        #pragma unroll
        for (int nt = 0; nt < 4; ++nt)
            #pragma unroll
            for (int r = 0; r < 4; ++r) {
                float v = sacc[nt][r] * 0.125f;   // 1/sqrt(64)
                if (diag && (nt * 16 + (h4 << 2) + r > (w << 4) + c15))
                    v = -1e30f;
                p16[nt * 4 + r] = v;
            }

        // ---- online softmax, lane-local q-row; reduce across h4 groups
        float mx = p16[0];
        #pragma unroll
        for (int i = 1; i < 16; ++i) mx = fmaxf(mx, p16[i]);
        mx = fmaxf(mx, __shfl_xor(mx, 16, 64));
        mx = fmaxf(mx, __shfl_xor(mx, 32, 64));
        if (!__all(mx <= mr)) {          // exact: skipped iff alpha==1 wave-wide
            const float mnew = fmaxf(mr, mx);
            const float alpha = __expf(mr - mnew);
            mr = mnew;
            lr *= alpha;
            #pragma unroll
            for (int et = 0; et < 4; ++et) accO[et] *= alpha;
        }
        float rs = 0.0f;
        #pragma unroll
        for (int i = 0; i < 16; ++i) {
            p16[i] = __expf(p16[i] - mr);
            rs += p16[i];
        }
        rs += __shfl_xor(rs, 16, 64);
        rs += __shfl_xor(rs, 32, 64);
        lr += rs;

        // ---- P bf16 B-fragments, in registers (k-order g_c)
        short8 pb[2];
        #pragma unroll
        for (int c = 0; c < 2; ++c)
            #pragma unroll
            for (int i = 0; i < 8; ++i)
                pb[c][i] = (short)f2bf(p16[8 * c + i]);

        // ---- O += V^T x P : A = fragment-ordered V, ONE b128 per fragment
        #pragma unroll
        for (int c = 0; c < 2; ++c) {
            const int fs = (c << 2) + h4;
            #pragma unroll
            for (int et = 0; et < 4; ++et) {
                const int e = (et << 4) + c15;
                const short8 vf = *(const short8*)&Vs[(e << 6) + ((fs ^ (e & 7)) << 3)];
                accO[et] = __builtin_amdgcn_mfma_f32_16x16x32_bf16(vf, pb[c], accO[et], 0, 0, 0);
            }
        }
    }

    // ---- epilogue: normalize (lane-local l), write bf16 y [B,S,D]
    const int bq = bh >> 4, hh = bh & 15;
    const float inv = 1.0f / lr;
    short* orow = yb + ((size_t)bq * S_LEN + myq) * DMODEL + hh * HD;
    #pragma unroll
    for (int et = 0; et < 4; ++et) {
        short4_t o;
        #pragma unroll
        for (int r = 0; r < 4; ++r) o[r] = (short)f2bf(accO[et][r] * inv);
        *(short4_t*)&orow[(et << 4) + (h4 << 2)] = o;
    }
}

// ---------------------------------------------------------------------------
// Workspace (48 MB):
//   [ 0, 8M) q bf16 [B,H,S,hd]   [ 8,16M) k bf16   [16,24M) v bf16
//   [24,32M) v^T bf16 [B,H,hd,S] (fragment-ordered windows)
//   [32,40M) xb (cast->gemm1) / yb (attn->gemm2)  — disjoint in time
//   [40,46M) wab (cast->gemm1)
//   [46,48M) wpb (cast->gemm2)
// ---------------------------------------------------------------------------
extern "C" void kernel_launch(void* const* d_in, const int* in_sizes, int n_in,
                              void* d_out, int out_size, void* d_ws, size_t ws_size,
                              hipStream_t stream) {
    const float* x      = (const float*)d_in[0];
    const float* w_attn = (const float*)d_in[1];
    const float* b_attn = (const float*)d_in[2];
    const float* w_proj = (const float*)d_in[3];
    const float* b_proj = (const float*)d_in[4];
    float* out = (float*)d_out;

    const int B = 2;
    const int M = B * S_LEN;

    char* wsb = (char*)d_ws;
    short* qw  = (short*)(wsb);
    short* kw  = (short*)(wsb + (8u << 20));
    short* vw  = (short*)(wsb + (16u << 20));
    short* vtw = (short*)(wsb + (24u << 20));
    short* xb  = (short*)(wsb + (32u << 20));
    short* yb  = (short*)(wsb + (32u << 20));
    short* wab = (short*)(wsb + (40u << 20));
    short* wpb = (short*)(wsb + (46u << 20));

    cast3_f32_bf16<<<dim3(4096), 256, 0, stream>>>(x, w_attn, w_proj, xb, wab, wpb);

    dim3 g1(3 * DMODEL / 128, M / 128);
    gemm_mfma<true><<<g1, 256, 0, stream>>>(xb, wab, b_attn, nullptr,
                                            3 * DMODEL, DMODEL, qw, kw, vw);

    transpose_v<<<dim3(2 * NHEAD * (S_LEN / 64)), 256, 0, stream>>>(vw, vtw);

    flash_attn_mfma<<<dim3(2 * NHEAD * (S_LEN / 64)), 256, 0, stream>>>(qw, kw, vtw, yb);

    dim3 g3(DMODEL / 128, M / 128);
    gemm_mfma<false><<<g3, 256, 0, stream>>>(yb, wpb, b_proj, out,
                                             DMODEL, DMODEL,
                                             nullptr, nullptr, nullptr);
}